// Round 1
// baseline (1873.502 us; speedup 1.0000x reference)
//
#include <hip/hip_runtime.h>

#define CUBE 32

__device__ __forceinline__ float sgpr_f(float v) {
    int i = __builtin_amdgcn_readfirstlane(__float_as_int(v));
    return __int_as_float(i);
}

// ---------------- Kernel A: surface = x @ W_in^T + b_in ----------------
// x [1024][784], W_in [1024][784] -> surface [1024][1024]
__global__ __launch_bounds__(256) void in_gemm(
    const float* __restrict__ x,
    const float* __restrict__ W_in,
    const float* __restrict__ b_in,
    float* __restrict__ surface)
{
    __shared__ __align__(16) float As[16][68];
    __shared__ __align__(16) float Bs[16][68];
    const int t  = threadIdx.x;
    const int tx = t & 15, ty = t >> 4;
    const int bn = blockIdx.x * 64;   // neuron tile
    const int bb = blockIdx.y * 64;   // batch tile

    float acc[4][4];
#pragma unroll
    for (int i = 0; i < 4; ++i)
#pragma unroll
        for (int j = 0; j < 4; ++j) acc[i][j] = 0.0f;

    for (int k0 = 0; k0 < 784; k0 += 16) {
        const int e  = t * 4;
        const int r  = e >> 4;
        const int kk = e & 15;           // 0,4,8,12
        float4 av = *(const float4*)&x[(size_t)(bb + r) * 784 + k0 + kk];
        float4 bv = *(const float4*)&W_in[(size_t)(bn + r) * 784 + k0 + kk];
        As[kk + 0][r] = av.x; As[kk + 1][r] = av.y; As[kk + 2][r] = av.z; As[kk + 3][r] = av.w;
        Bs[kk + 0][r] = bv.x; Bs[kk + 1][r] = bv.y; Bs[kk + 2][r] = bv.z; Bs[kk + 3][r] = bv.w;
        __syncthreads();
#pragma unroll
        for (int kki = 0; kki < 16; ++kki) {
            float4 a = *(const float4*)&As[kki][ty * 4];
            float4 b = *(const float4*)&Bs[kki][tx * 4];
            float aa[4] = {a.x, a.y, a.z, a.w};
            float bbv[4] = {b.x, b.y, b.z, b.w};
#pragma unroll
            for (int i = 0; i < 4; ++i)
#pragma unroll
                for (int j = 0; j < 4; ++j)
                    acc[i][j] = fmaf(aa[i], bbv[j], acc[i][j]);
        }
        __syncthreads();
    }
#pragma unroll
    for (int i = 0; i < 4; ++i) {
        const int row = bb + ty * 4 + i;
#pragma unroll
        for (int j = 0; j < 4; ++j) {
            const int col = bn + tx * 4 + j;
            surface[(size_t)row * 1024 + col] = acc[i][j] + b_in[col];
        }
    }
}

// ---------------- Kernel B: 30-step cube evolution + output GEMM ----------------
// One block per batch. Thread (y,x) owns the d-column (32 values in registers).
// LDS holds the previous state, zero-padded in y,x for SAME conv padding.
__global__ __launch_bounds__(1024) void cube_evolve(
    const float* __restrict__ surface,   // [1024][1024]
    const float* __restrict__ conv_w,    // [27]  (kd,ky,kx)
    const float* __restrict__ nbias,     // [32768] (d,y,x)
    const float* __restrict__ W_out,     // [10][32768]
    const float* __restrict__ b_out,     // [10]
    const int*   __restrict__ steps_p,   // [1]
    float* __restrict__ out)             // [1024][10]
{
    __shared__ float S[32][34][34];      // 147,968 B
    __shared__ float red[10][16];

    const int b   = blockIdx.x;
    const int tx  = threadIdx.x;         // x
    const int ty  = threadIdx.y;         // y
    const int tid = ty * 32 + tx;
    const int steps = steps_p[0];

    // zero entire LDS cube (borders must be 0, and they stay 0)
    for (int i = tid; i < 32 * 34 * 34; i += 1024) ((float*)S)[i] = 0.0f;

    // conv weights -> SGPRs (uniform)
    float w[27];
#pragma unroll
    for (int i = 0; i < 27; ++i) w[i] = sgpr_f(conv_w[i]);

    float s[32];
#pragma unroll
    for (int d = 0; d < 32; ++d) s[d] = 0.0f;

    const float surf = surface[(size_t)b * 1024 + tid];

    __syncthreads();

    for (int st = 0; st < steps; ++st) {
        // publish old state
#pragma unroll
        for (int d = 0; d < 32; ++d) S[d][ty + 1][tx + 1] = s[d];
        __syncthreads();

        float acc[3] = {0.0f, 0.0f, 0.0f};
        // sweep input planes; plane p contributes to outputs p-1 (kd=2), p (kd=1), p+1 (kd=0)
#pragma unroll
        for (int p = 0; p < 32; ++p) {
            float v[9];
#pragma unroll
            for (int ky = 0; ky < 3; ++ky)
#pragma unroll
                for (int kx = 0; kx < 3; ++kx)
                    v[ky * 3 + kx] = S[p][ty + ky][tx + kx];

            if (p < 31) {
#pragma unroll
                for (int j = 0; j < 9; ++j)
                    acc[(p + 1) % 3] = fmaf(w[0 * 9 + j], v[j], acc[(p + 1) % 3]);
            }
#pragma unroll
            for (int j = 0; j < 9; ++j)
                acc[p % 3] = fmaf(w[1 * 9 + j], v[j], acc[p % 3]);
            if (p >= 1) {
#pragma unroll
                for (int j = 0; j < 9; ++j)
                    acc[(p + 2) % 3] = fmaf(w[2 * 9 + j], v[j], acc[(p + 2) % 3]);
                // finalize out[p-1]
                const int q = p - 1;
                float inj = nbias[q * 1024 + tid] + (q == 0 ? surf : 0.0f);
                float pre = acc[(p + 2) % 3] + inj;
                float t  = __builtin_amdgcn_exp2f(pre * 2.8853900817779268f); // e^(2x)
                float h  = 1.0f - 2.0f * __builtin_amdgcn_rcpf(t + 1.0f);     // tanh
                s[q] = 0.5f * (s[q] + h);
                acc[(p + 2) % 3] = 0.0f;
            }
        }
        { // finalize out[31] (accumulated in slot 31%3 from input planes 30,31)
            float inj = nbias[31 * 1024 + tid];
            float pre = acc[31 % 3] + inj;
            float t  = __builtin_amdgcn_exp2f(pre * 2.8853900817779268f);
            float h  = 1.0f - 2.0f * __builtin_amdgcn_rcpf(t + 1.0f);
            s[31] = 0.5f * (s[31] + h);
        }
        __syncthreads();
    }

    // ---- fused output GEMM: out[b][o] = sum_d s[d] * W_out[o][d*1024+tid] + b_out[o]
    float partial[10];
#pragma unroll
    for (int o = 0; o < 10; ++o) partial[o] = 0.0f;
#pragma unroll
    for (int o = 0; o < 10; ++o) {
        const float* wrow = &W_out[(size_t)o * 32768 + tid];
#pragma unroll
        for (int d = 0; d < 32; ++d)
            partial[o] = fmaf(s[d], wrow[d * 1024], partial[o]);
    }

    const int lane = tid & 63, wid = tid >> 6;
#pragma unroll
    for (int o = 0; o < 10; ++o) {
        float vv = partial[o];
#pragma unroll
        for (int off = 32; off >= 1; off >>= 1) vv += __shfl_down(vv, off, 64);
        if (lane == 0) red[o][wid] = vv;
    }
    __syncthreads();
    if (tid < 10) {
        float sum = b_out[tid];
#pragma unroll
        for (int wdx = 0; wdx < 16; ++wdx) sum += red[tid][wdx];
        out[(size_t)b * 10 + tid] = sum;
    }
}

// ---------------- launcher ----------------
extern "C" void kernel_launch(void* const* d_in, const int* in_sizes, int n_in,
                              void* d_out, int out_size, void* d_ws, size_t ws_size,
                              hipStream_t stream) {
    const float* x      = (const float*)d_in[0];
    const float* W_in   = (const float*)d_in[1];
    const float* b_in   = (const float*)d_in[2];
    const float* conv_w = (const float*)d_in[3];
    const float* nbias  = (const float*)d_in[4];
    const float* W_out  = (const float*)d_in[5];
    const float* b_out  = (const float*)d_in[6];
    const int*   steps  = (const int*)d_in[7];
    float* out = (float*)d_out;
    float* surface = (float*)d_ws;   // 1024*1024 f32 = 4 MB scratch

    in_gemm<<<dim3(16, 16), 256, 0, stream>>>(x, W_in, b_in, surface);
    cube_evolve<<<1024, dim3(32, 32), 0, stream>>>(surface, conv_w, nbias,
                                                   W_out, b_out, steps, out);
}

// Round 2
// 1812.813 us; speedup vs baseline: 1.0335x; 1.0335x over previous
//
#include <hip/hip_runtime.h>

#define CUBE 32

__device__ __forceinline__ float sgpr_f(float v) {
    int i = __builtin_amdgcn_readfirstlane(__float_as_int(v));
    return __int_as_float(i);
}

// ---------------- Kernel A: surface = x @ W_in^T + b_in ----------------
// x [1024][784], W_in [1024][784] -> surface [1024][1024]
__global__ __launch_bounds__(256) void in_gemm(
    const float* __restrict__ x,
    const float* __restrict__ W_in,
    const float* __restrict__ b_in,
    float* __restrict__ surface)
{
    __shared__ __align__(16) float As[16][68];
    __shared__ __align__(16) float Bs[16][68];
    const int t  = threadIdx.x;
    const int tx = t & 15, ty = t >> 4;
    const int bn = blockIdx.x * 64;   // neuron tile
    const int bb = blockIdx.y * 64;   // batch tile

    float acc[4][4];
#pragma unroll
    for (int i = 0; i < 4; ++i)
#pragma unroll
        for (int j = 0; j < 4; ++j) acc[i][j] = 0.0f;

    for (int k0 = 0; k0 < 784; k0 += 16) {
        const int e  = t * 4;
        const int r  = e >> 4;
        const int kk = e & 15;           // 0,4,8,12
        float4 av = *(const float4*)&x[(size_t)(bb + r) * 784 + k0 + kk];
        float4 bv = *(const float4*)&W_in[(size_t)(bn + r) * 784 + k0 + kk];
        As[kk + 0][r] = av.x; As[kk + 1][r] = av.y; As[kk + 2][r] = av.z; As[kk + 3][r] = av.w;
        Bs[kk + 0][r] = bv.x; Bs[kk + 1][r] = bv.y; Bs[kk + 2][r] = bv.z; Bs[kk + 3][r] = bv.w;
        __syncthreads();
#pragma unroll
        for (int kki = 0; kki < 16; ++kki) {
            float4 a = *(const float4*)&As[kki][ty * 4];
            float4 b = *(const float4*)&Bs[kki][tx * 4];
            float aa[4] = {a.x, a.y, a.z, a.w};
            float bbv[4] = {b.x, b.y, b.z, b.w};
#pragma unroll
            for (int i = 0; i < 4; ++i)
#pragma unroll
                for (int j = 0; j < 4; ++j)
                    acc[i][j] = fmaf(aa[i], bbv[j], acc[i][j]);
        }
        __syncthreads();
    }
#pragma unroll
    for (int i = 0; i < 4; ++i) {
        const int row = bb + ty * 4 + i;
#pragma unroll
        for (int j = 0; j < 4; ++j) {
            const int col = bn + tx * 4 + j;
            surface[(size_t)row * 1024 + col] = acc[i][j] + b_in[col];
        }
    }
}

// ---------------- Kernel B: 30-step cube evolution + output GEMM ----------------
// One block per batch. Thread (y,x) owns the d-column (32 values in registers).
// LDS holds the previous state, zero-padded in y,x for SAME conv padding.
// launch_bounds(1024, 4): 16 waves/block = 4 waves/EU exactly -> 128-VGPR
// budget so s[32] + nb[32] + window stay in registers (r1 spilled at 64 VGPRs:
// WRITE_SIZE was 838 MB of scratch traffic).
__global__ __launch_bounds__(1024, 4) void cube_evolve(
    const float* __restrict__ surface,   // [1024][1024]
    const float* __restrict__ conv_w,    // [27]  (kd,ky,kx)
    const float* __restrict__ nbias,     // [32768] (d,y,x)
    const float* __restrict__ W_out,     // [10][32768]
    const float* __restrict__ b_out,     // [10]
    const int*   __restrict__ steps_p,   // [1]
    float* __restrict__ out)             // [1024][10]
{
    __shared__ float S[32][34][34];      // 147,968 B
    __shared__ float red[10][16];

    const int b   = blockIdx.x;
    const int tx  = threadIdx.x;         // x
    const int ty  = threadIdx.y;         // y
    const int tid = ty * 32 + tx;
    const int steps = steps_p[0];

    // zero entire LDS cube (borders must be 0, and they stay 0)
    for (int i = tid; i < 32 * 34 * 34; i += 1024) ((float*)S)[i] = 0.0f;

    // conv weights -> SGPRs (uniform)
    float w[27];
#pragma unroll
    for (int i = 0; i < 27; ++i) w[i] = sgpr_f(conv_w[i]);

    // per-thread injection column: nbias(+surface on plane 0), in registers
    float nb[32];
#pragma unroll
    for (int d = 0; d < 32; ++d) nb[d] = nbias[d * 1024 + tid];
    nb[0] += surface[(size_t)b * 1024 + tid];

    float s[32];
#pragma unroll
    for (int d = 0; d < 32; ++d) s[d] = 0.0f;

    __syncthreads();

    for (int st = 0; st < steps; ++st) {
        // publish old state
#pragma unroll
        for (int d = 0; d < 32; ++d) S[d][ty + 1][tx + 1] = s[d];
        __syncthreads();

        float acc[3] = {0.0f, 0.0f, 0.0f};
        // sweep input planes; plane p contributes to outputs p-1 (kd=2), p (kd=1), p+1 (kd=0)
#pragma unroll
        for (int p = 0; p < 32; ++p) {
            float v[9];
#pragma unroll
            for (int ky = 0; ky < 3; ++ky)
#pragma unroll
                for (int kx = 0; kx < 3; ++kx)
                    v[ky * 3 + kx] = S[p][ty + ky][tx + kx];

            if (p < 31) {
#pragma unroll
                for (int j = 0; j < 9; ++j)
                    acc[(p + 1) % 3] = fmaf(w[0 * 9 + j], v[j], acc[(p + 1) % 3]);
            }
#pragma unroll
            for (int j = 0; j < 9; ++j)
                acc[p % 3] = fmaf(w[1 * 9 + j], v[j], acc[p % 3]);
            if (p >= 1) {
#pragma unroll
                for (int j = 0; j < 9; ++j)
                    acc[(p + 2) % 3] = fmaf(w[2 * 9 + j], v[j], acc[(p + 2) % 3]);
                // finalize out[p-1]
                const int q = p - 1;
                float pre = acc[(p + 2) % 3] + nb[q];
                float t  = __builtin_amdgcn_exp2f(pre * 2.8853900817779268f); // e^(2x)
                float h  = 1.0f - 2.0f * __builtin_amdgcn_rcpf(t + 1.0f);     // tanh
                s[q] = 0.5f * (s[q] + h);
                acc[(p + 2) % 3] = 0.0f;
            }
        }
        { // finalize out[31] (accumulated in slot 31%3 from input planes 30,31)
            float pre = acc[31 % 3] + nb[31];
            float t  = __builtin_amdgcn_exp2f(pre * 2.8853900817779268f);
            float h  = 1.0f - 2.0f * __builtin_amdgcn_rcpf(t + 1.0f);
            s[31] = 0.5f * (s[31] + h);
        }
        __syncthreads();
    }

    // ---- fused output GEMM: out[b][o] = sum_d s[d] * W_out[o][d*1024+tid] + b_out[o]
    float partial[10];
#pragma unroll
    for (int o = 0; o < 10; ++o) partial[o] = 0.0f;
#pragma unroll
    for (int o = 0; o < 10; ++o) {
        const float* wrow = &W_out[(size_t)o * 32768 + tid];
#pragma unroll
        for (int d = 0; d < 32; ++d)
            partial[o] = fmaf(s[d], wrow[d * 1024], partial[o]);
    }

    const int lane = tid & 63, wid = tid >> 6;
#pragma unroll
    for (int o = 0; o < 10; ++o) {
        float vv = partial[o];
#pragma unroll
        for (int off = 32; off >= 1; off >>= 1) vv += __shfl_down(vv, off, 64);
        if (lane == 0) red[o][wid] = vv;
    }
    __syncthreads();
    if (tid < 10) {
        float sum = b_out[tid];
#pragma unroll
        for (int wdx = 0; wdx < 16; ++wdx) sum += red[tid][wdx];
        out[(size_t)b * 10 + tid] = sum;
    }
}

// ---------------- launcher ----------------
extern "C" void kernel_launch(void* const* d_in, const int* in_sizes, int n_in,
                              void* d_out, int out_size, void* d_ws, size_t ws_size,
                              hipStream_t stream) {
    const float* x      = (const float*)d_in[0];
    const float* W_in   = (const float*)d_in[1];
    const float* b_in   = (const float*)d_in[2];
    const float* conv_w = (const float*)d_in[3];
    const float* nbias  = (const float*)d_in[4];
    const float* W_out  = (const float*)d_in[5];
    const float* b_out  = (const float*)d_in[6];
    const int*   steps  = (const int*)d_in[7];
    float* out = (float*)d_out;
    float* surface = (float*)d_ws;   // 1024*1024 f32 = 4 MB scratch

    in_gemm<<<dim3(16, 16), 256, 0, stream>>>(x, W_in, b_in, surface);
    cube_evolve<<<1024, dim3(32, 32), 0, stream>>>(surface, conv_w, nbias,
                                                   W_out, b_out, steps, out);
}